// Round 11
// baseline (175.484 us; speedup 1.0000x reference)
//
#include <hip/hip_runtime.h>
#include <hip/hip_bf16.h>
#include <stdint.h>

// B=32768 queries, M=4096 memory rows, D=128.
//   logits = Q @ M^T ; attn = softmax(logits) ; out = attn @ M
// Flash-style fused kernel. bf16x3-split MFMA QK^T (near-fp32), bf16 PV.
// v11: halve LDS demand by doubling q-rows per wave (64 q = 2 groups of 32).
// Rounds 6-10 invariant: ~2750 cyc/tile/CU = LDS(1152) + MFMA(516) + VALU
// serialized; pipes don't overlap at HIP level. So cut demand: one 24KB
// K/V tile read now feeds 64 MFMAs (2 q-groups) instead of 32 -> tile
// visits halve (256 blocks x 64 tiles). V frags read once, used by both
// groups' PV. 1 block/CU (512-reg budget): Q 128 + O 128 + S 64 + K-half
// batch 32 + pf 16 + misc ~ 410 regs. M-split 2 + lightweight merge.

typedef float   f32x16 __attribute__((ext_vector_type(16)));
typedef short   bf16x8 __attribute__((ext_vector_type(8)));
typedef uint32_t u32;

#define AS1 __attribute__((address_space(1)))
#define AS3 __attribute__((address_space(3)))

#define D_DIM 128
#define B_ROWS 32768
#define TILE_HW 12288     // halfwords per 32-row tile: [khi 4096|klo 4096|v 4096]
#define HALF_TILES 64     // tiles per block

#if __has_builtin(__builtin_amdgcn_exp2f)
#define EXP2F(x) __builtin_amdgcn_exp2f(x)
#else
#define EXP2F(x) exp2f(x)
#endif

__device__ __forceinline__ uint16_t f32_to_bf16_rne(float x) {
    u32 u = __float_as_uint(x);
    u32 r = u + 0x7fffu + ((u >> 16) & 1u);
    return (uint16_t)(r >> 16);
}
__device__ __forceinline__ float bf16_to_f32(uint16_t h) {
    return __uint_as_float(((u32)h) << 16);
}

// ---------------------------------------------------------------------------
// Prep: memory -> interleaved fragment-linear bf16 tiles in d_ws.
// Per tile mt (24576 B): [0,8K) khi frags, [8K,16K) klo frags, [16K,24K) v frags.
// ---------------------------------------------------------------------------
__global__ void prep_frags(const float* __restrict__ mem,
                           uint16_t* __restrict__ kv) {
    int t = blockIdx.x * blockDim.x + threadIdx.x;  // 0..65535
    int lane = t & 63;
    int fi = t >> 6;                                // 0..1023
    int f8 = fi & 7, mt = fi >> 3;
    size_t base = (size_t)mt * TILE_HW;
    {   // K fragment (hi/lo split)
        int m  = mt * 32 + (lane & 31);
        int d0 = f8 * 16 + (lane >> 5) * 8;
        const float* src = mem + (size_t)m * D_DIM + d0;
        #pragma unroll
        for (int e = 0; e < 8; ++e) {
            float x = src[e];
            uint16_t hb = f32_to_bf16_rne(x);
            kv[base + f8 * 512 + lane * 8 + e] = hb;
            kv[base + 4096 + f8 * 512 + lane * 8 + e] =
                f32_to_bf16_rne(x - bf16_to_f32(hb));
        }
    }
    {   // V^T fragment (plain bf16)
        int dt = fi & 3, ks = (fi >> 2) & 1;
        int d  = dt * 32 + (lane & 31);
        int m0 = mt * 32 + ks * 16 + (lane >> 5) * 8;
        #pragma unroll
        for (int e = 0; e < 8; ++e)
            kv[base + 8192 + f8 * 512 + lane * 8 + e] =
                f32_to_bf16_rne(mem[(size_t)(m0 + e) * D_DIM + d]);
    }
}

// ---------------------------------------------------------------------------
// Main kernel: 256 blocks x 256 threads (4 waves, 1 block/CU). Block bx:
// q-chunk bx>>1 (256 rows: wave w group g owns rows +(w+4g)*32), memory
// half bx&1 (64 tiles). LDS double-buffered 24KB tiles (48 KB).
// ---------------------------------------------------------------------------

#define STAGE(t_, wb_) do {                                                   \
    const char* g_ = (const char*)(kv + (size_t)(tilebase + (t_)) * TILE_HW); \
    char* l_ = (char*)&sbuf[wb_][0];                                          \
    _Pragma("unroll")                                                         \
    for (int j_ = 0; j_ < 6; ++j_) {                                          \
        int ch_ = wave * 6 + j_;                                              \
        __builtin_amdgcn_global_load_lds(                                     \
            (const AS1 char*)(g_ + ch_ * 1024 + lane * 16),                   \
            (AS3 char*)(l_ + ch_ * 1024), 16, 0, 0);                          \
    }                                                                         \
} while (0)

#define MFMA_BF16(a_, b_, c_) __builtin_amdgcn_mfma_f32_32x32x16_bf16(a_, b_, c_, 0, 0, 0)

// Load 128 f32 of one q-row-group, fold log2e, split bf16 hi/lo.
#define QPREP(QH, QL, qrow_) do {                                             \
    const float LOG2E = 1.44269504088896340736f;                              \
    _Pragma("unroll")                                                         \
    for (int kk = 0; kk < 8; ++kk) {                                          \
        const float* src = qin + (size_t)(qrow_) * D_DIM + kk * 16 + hi32 * 8;\
        float4 a = *(const float4*)(src);                                     \
        float4 b = *(const float4*)(src + 4);                                 \
        float xs[8] = {a.x, a.y, a.z, a.w, b.x, b.y, b.z, b.w};               \
        _Pragma("unroll")                                                     \
        for (int e = 0; e < 8; ++e) {                                         \
            float x = xs[e] * LOG2E;                                          \
            uint16_t hb = f32_to_bf16_rne(x);                                 \
            QH[kk][e] = (short)hb;                                            \
            QL[kk][e] = (short)f32_to_bf16_rne(x - bf16_to_f32(hb));          \
        }                                                                     \
    }                                                                         \
} while (0)

// Online softmax for one group (Sᵀ layout: q = lane&31) -> m/l/O-rescale + pf.
#define SMX(s_, mr_, lr_, OA_, OB_, OC_, OD_, PF0, PF1) do {                  \
    float a0=fmaxf(s_[0],s_[1]),  a1=fmaxf(s_[2],s_[3]);                      \
    float a2=fmaxf(s_[4],s_[5]),  a3=fmaxf(s_[6],s_[7]);                      \
    float a4=fmaxf(s_[8],s_[9]),  a5=fmaxf(s_[10],s_[11]);                    \
    float a6=fmaxf(s_[12],s_[13]),a7=fmaxf(s_[14],s_[15]);                    \
    float tmax = fmaxf(fmaxf(fmaxf(a0,a1),fmaxf(a2,a3)),                      \
                       fmaxf(fmaxf(a4,a5),fmaxf(a6,a7)));                     \
    tmax = fmaxf(tmax, __shfl_xor(tmax, 32));                                 \
    if (__any(tmax > mr_ + 8.0f)) {     /* defer-max (T13) */                 \
        float mn = fmaxf(mr_, tmax);                                          \
        float fr = EXP2F(mr_ - mn);                                           \
        mr_ = mn; lr_ *= fr;                                                  \
        _Pragma("unroll")                                                     \
        for (int r_ = 0; r_ < 16; ++r_) {                                     \
            OA_[r_] *= fr; OB_[r_] *= fr; OC_[r_] *= fr; OD_[r_] *= fr;       \
        }                                                                     \
    }                                                                         \
    _Pragma("unroll")                                                         \
    for (int r_ = 0; r_ < 16; ++r_) s_[r_] = EXP2F(s_[r_] - mr_);             \
    { float q0s=s_[0]+s_[1],  q1s=s_[2]+s_[3],  q2s=s_[4]+s_[5],  q3s=s_[6]+s_[7];   \
      float q4s=s_[8]+s_[9],  q5s=s_[10]+s_[11],q6s=s_[12]+s_[13],q7s=s_[14]+s_[15]; \
      lr_ += ((q0s+q1s)+(q2s+q3s)) + ((q4s+q5s)+(q6s+q7s)); }                 \
    u32 c_[8];                                                                \
    _Pragma("unroll")                                                         \
    for (int j_ = 0; j_ < 8; ++j_)                                            \
        asm("v_cvt_pk_bf16_f32 %0, %1, %2"                                    \
            : "=v"(c_[j_]) : "v"(s_[2*j_]), "v"(s_[2*j_+1]));                 \
    asm("v_permlane32_swap_b32 %0, %1" : "+v"(c_[0]), "+v"(c_[2]));           \
    asm("v_permlane32_swap_b32 %0, %1" : "+v"(c_[1]), "+v"(c_[3]));           \
    asm("v_permlane32_swap_b32 %0, %1" : "+v"(c_[4]), "+v"(c_[6]));           \
    asm("v_permlane32_swap_b32 %0, %1" : "+v"(c_[5]), "+v"(c_[7]));           \
    { u32 w_[4] = {c_[0], c_[1], c_[2], c_[3]}; __builtin_memcpy(&PF0, w_, 16); } \
    { u32 w_[4] = {c_[4], c_[5], c_[6], c_[7]}; __builtin_memcpy(&PF1, w_, 16); } \
} while (0)

#define PSTORE_TILE(prow_, Ot_, t_, rinv_) do {                               \
    _Pragma("unroll")                                                         \
    for (int g_ = 0; g_ < 4; ++g_) {                                          \
        float4 v_;                                                            \
        v_.x = Ot_[4*g_+0] * rinv_;                                           \
        v_.y = Ot_[4*g_+1] * rinv_;                                           \
        v_.z = Ot_[4*g_+2] * rinv_;                                           \
        v_.w = Ot_[4*g_+3] * rinv_;                                           \
        int d_ = (t_) * 32 + 8 * g_ + 4 * hi32;                               \
        *(float4*)((prow_) + d_) = v_;                                        \
    }                                                                         \
} while (0)

__global__ __launch_bounds__(256, 1)
void attn_main(const float* __restrict__ qin,
               const uint16_t* __restrict__ kv,
               float* __restrict__ out0,      // part-0 un-normalized O (= d_out)
               float* __restrict__ pout1,     // [B_ROWS][128] part-1 partial
               float2* __restrict__ pml) {    // [2][B_ROWS] (m, l)
    __shared__ uint16_t sbuf[2][TILE_HW];   // 2 x 24 KB = 48 KB

    const int lane = threadIdx.x & 63;
    const int wave = threadIdx.x >> 6;
    const int half = blockIdx.x & 1;
    const int tilebase = half * HALF_TILES;
    const int qbase = (blockIdx.x >> 1) * 256;
    const int qrow0 = qbase + wave * 32 + (lane & 31);        // group 0
    const int qrow1 = qbase + (wave + 4) * 32 + (lane & 31);  // group 1
    const int hi32 = lane >> 5;

    bf16x8 qh0[8], ql0[8], qh1[8], ql1[8];
    QPREP(qh0, ql0, qrow0);
    QPREP(qh1, ql1, qrow1);

    f32x16 O0a, O1a, O2a, O3a, O0b, O1b, O2b, O3b;
    #pragma unroll
    for (int i = 0; i < 16; ++i) {
        O0a[i]=0.f; O1a[i]=0.f; O2a[i]=0.f; O3a[i]=0.f;
        O0b[i]=0.f; O1b[i]=0.f; O2b[i]=0.f; O3b[i]=0.f;
    }
    float m0 = -1e30f, l0 = 0.f, m1 = -1e30f, l1 = 0.f;

    STAGE(0, 0);
    __syncthreads();

    #pragma unroll 1
    for (int t = 0; t < HALF_TILES; ++t) {
        const int rb = t & 1;
        if (t + 1 < HALF_TILES) STAGE(t + 1, rb ^ 1);
        const uint16_t* bp = &sbuf[rb][0] + lane * 8;

        // ---- QK^T for both q-groups: bf16x3 split, 4 chains, K in 2 half-batches
        f32x16 sh0, sl0, sh1, sl1;
        #pragma unroll
        for (int i = 0; i < 16; ++i) { sh0[i]=0.f; sl0[i]=0.f; sh1[i]=0.f; sl1[i]=0.f; }
        #pragma unroll
        for (int hb = 0; hb < 2; ++hb) {
            bf16x8 kh[4], kl[4];
            #pragma unroll
            for (int k4 = 0; k4 < 4; ++k4) {
                kh[k4] = *(const bf16x8*)(bp + (hb * 4 + k4) * 512);
                kl[k4] = *(const bf16x8*)(bp + 4096 + (hb * 4 + k4) * 512);
            }
            __builtin_amdgcn_s_setprio(1);
            #pragma unroll
            for (int k4 = 0; k4 < 4; ++k4) {
                const int kk = hb * 4 + k4;
                sh0 = MFMA_BF16(kh[k4], qh0[kk], sh0);
                sh1 = MFMA_BF16(kh[k4], qh1[kk], sh1);
                sl0 = MFMA_BF16(kh[k4], ql0[kk], sl0);
                sl1 = MFMA_BF16(kh[k4], ql1[kk], sl1);
                sl0 = MFMA_BF16(kl[k4], qh0[kk], sl0);
                sl1 = MFMA_BF16(kl[k4], qh1[kk], sl1);
            }
            __builtin_amdgcn_s_setprio(0);
        }
        f32x16 s0 = sh0 + sl0;
        f32x16 s1 = sh1 + sl1;

        // ---- two independent online softmaxes ----
        bf16x8 pf00, pf01, pf10, pf11;
        SMX(s0, m0, l0, O0a, O1a, O2a, O3a, pf00, pf01);
        SMX(s1, m1, l1, O0b, O1b, O2b, O3b, pf10, pf11);

        // ---- PV: each V frag read once, used by BOTH groups ----
        __builtin_amdgcn_s_setprio(1);
        {
            bf16x8 vf;
            vf = *(const bf16x8*)(bp + 8192 + 0*512);
            O0a = MFMA_BF16(vf, pf00, O0a); O0b = MFMA_BF16(vf, pf10, O0b);
            vf = *(const bf16x8*)(bp + 8192 + 1*512);
            O1a = MFMA_BF16(vf, pf00, O1a); O1b = MFMA_BF16(vf, pf10, O1b);
            vf = *(const bf16x8*)(bp + 8192 + 2*512);
            O2a = MFMA_BF16(vf, pf00, O2a); O2b = MFMA_BF16(vf, pf10, O2b);
            vf = *(const bf16x8*)(bp + 8192 + 3*512);
            O3a = MFMA_BF16(vf, pf00, O3a); O3b = MFMA_BF16(vf, pf10, O3b);
            vf = *(const bf16x8*)(bp + 8192 + 4*512);
            O0a = MFMA_BF16(vf, pf01, O0a); O0b = MFMA_BF16(vf, pf11, O0b);
            vf = *(const bf16x8*)(bp + 8192 + 5*512);
            O1a = MFMA_BF16(vf, pf01, O1a); O1b = MFMA_BF16(vf, pf11, O1b);
            vf = *(const bf16x8*)(bp + 8192 + 6*512);
            O2a = MFMA_BF16(vf, pf01, O2a); O2b = MFMA_BF16(vf, pf11, O2b);
            vf = *(const bf16x8*)(bp + 8192 + 7*512);
            O3a = MFMA_BF16(vf, pf01, O3a); O3b = MFMA_BF16(vf, pf11, O3b);
        }
        __builtin_amdgcn_s_setprio(0);
        __syncthreads();
    }

    // ---- partial store (un-normalized O, plus m,l) for both groups ----
    l0 += __shfl_xor(l0, 32);
    l1 += __shfl_xor(l1, 32);
    float* base = (half == 0) ? out0 : pout1;
    float* prow0 = base + (size_t)qrow0 * D_DIM;
    float* prow1 = base + (size_t)qrow1 * D_DIM;
    PSTORE_TILE(prow0, O0a, 0, 1.0f); PSTORE_TILE(prow0, O1a, 1, 1.0f);
    PSTORE_TILE(prow0, O2a, 2, 1.0f); PSTORE_TILE(prow0, O3a, 3, 1.0f);
    PSTORE_TILE(prow1, O0b, 0, 1.0f); PSTORE_TILE(prow1, O1b, 1, 1.0f);
    PSTORE_TILE(prow1, O2b, 2, 1.0f); PSTORE_TILE(prow1, O3b, 3, 1.0f);
    if (lane < 32) {
        pml[(size_t)half * B_ROWS + qrow0] = make_float2(m0, l0);
        pml[(size_t)half * B_ROWS + qrow1] = make_float2(m1, l1);
    }
}

// ---------------------------------------------------------------------------
// Merge: out = (P0*w0 + P1*w1) / (l0*w0 + l1*w1), w_i = exp2(m_i - max).
// P0 lives in d_out (in-place read-modify-write per thread's own float4).
// ---------------------------------------------------------------------------
__global__ __launch_bounds__(256)
void merge_halves(const float* __restrict__ pout1,
                  const float2* __restrict__ pml,
                  float* __restrict__ out) {
    int idx  = blockIdx.x * 256 + threadIdx.x;   // 0 .. 2^20-1
    int row  = idx >> 5;
    int c4   = idx & 31;
    float2 a = pml[row];
    float2 b = pml[B_ROWS + row];
    float mn = fmaxf(a.x, b.x);
    float wa = EXP2F(a.x - mn);
    float wb = EXP2F(b.x - mn);
    float rinv = 1.0f / (a.y * wa + b.y * wb);
    float4* O = (float4*)(out + (size_t)row * D_DIM) + c4;
    const float4* P1 = (const float4*)(pout1 + (size_t)row * D_DIM) + c4;
    float4 p0 = *O, p1 = *P1;
    float4 v;
    v.x = (p0.x * wa + p1.x * wb) * rinv;
    v.y = (p0.y * wa + p1.y * wb) * rinv;
    v.z = (p0.z * wa + p1.z * wb) * rinv;
    v.w = (p0.w * wa + p1.w * wb) * rinv;
    *O = v;
}

extern "C" void kernel_launch(void* const* d_in, const int* in_sizes, int n_in,
                              void* d_out, int out_size, void* d_ws, size_t ws_size,
                              hipStream_t stream) {
    const float* local_stats = (const float*)d_in[0];   // [32768,128] f32
    const float* memory      = (const float*)d_in[1];   // [4096,128]  f32
    float* out = (float*)d_out;                         // [32768,128] f32

    // ws layout: kv frags 3MB | part-1 partial O 16MB | pml 0.5MB
    uint16_t* kv   = (uint16_t*)d_ws;
    float*   pout1 = (float*)((char*)d_ws + 3 * 1024 * 1024);
    float2*  pml   = (float2*)((char*)pout1 + (size_t)B_ROWS * D_DIM * 4);

    prep_frags<<<256, 256, 0, stream>>>(memory, kv);
    attn_main<<<256, 256, 0, stream>>>(local_stats, kv, out, pout1, pml);
    merge_halves<<<4096, 256, 0, stream>>>(pout1, pml, out);
}

// Round 13
// 104.103 us; speedup vs baseline: 1.6857x; 1.6857x over previous
//
#include <hip/hip_runtime.h>
#include <hip/hip_bf16.h>
#include <stdint.h>

// B=32768 queries, M=4096 memory rows, D=128.
//   logits = Q @ M^T ; attn = softmax(logits) ; out = attn @ M
// v12b: FP16 single-pass flash kernel (v12 + compile fix: cvt_pkrtz via
// inline asm, the builtin returns __fp16 vector which mismatches _Float16).
// Rounds 6-11 invariant: 2756 cyc per 32-q tile-visit regardless of
// occupancy — serial chain (ds_read -> 16-deep bf16x3 MFMA chain -> softmax
// -> PV) under barrier quantization. fp16's 11-bit mantissa gives logit err
// ~sqrt(128)*2^-10 ~ 0.011 (vs threshold 0.093), so the bf16x3 split is
// unnecessary: QK = 8 MFMAs (two 4-deep chains), tile 16KB, ds_reads 16.
// Same v6/v9 skeleton: 512 blocks x 256 thr, 2-way M-split, 2 blocks/CU.

typedef float    f32x16 __attribute__((ext_vector_type(16)));
typedef _Float16 f16x8  __attribute__((ext_vector_type(8)));
typedef uint32_t u32;

#define AS1 __attribute__((address_space(1)))
#define AS3 __attribute__((address_space(3)))

#define D_DIM 128
#define B_ROWS 32768
#define TILE_HW 8192      // halfwords per 32-row tile: [K 4096 | V 4096]
#define HALF_TILES 64     // tiles per block

#if __has_builtin(__builtin_amdgcn_exp2f)
#define EXP2F(x) __builtin_amdgcn_exp2f(x)
#else
#define EXP2F(x) exp2f(x)
#endif

__device__ __forceinline__ uint16_t f32_to_f16_bits(float x) {
    _Float16 h = (_Float16)x;
    uint16_t r; __builtin_memcpy(&r, &h, 2);
    return r;
}

// ---------------------------------------------------------------------------
// Prep: memory -> fragment-linear fp16 tiles in d_ws.
// Per tile mt (16384 B): [0,8K) K frags, [8K,16K) V^T frags.
//   K frag kk: element = memory[mt*32 + (lane&31)][kk*16 + (lane>>5)*8 + e]
//   V frag f=ks*4+dt: element = memory[mt*32 + ks*16 + (lane>>5)*8 + e][dt*32 + (lane&31)]
// ---------------------------------------------------------------------------
__global__ void prep_frags(const float* __restrict__ mem,
                           uint16_t* __restrict__ kv) {
    int t = blockIdx.x * blockDim.x + threadIdx.x;  // 0..65535
    int lane = t & 63;
    int fi = t >> 6;                                // 0..1023
    int f8 = fi & 7, mt = fi >> 3;
    size_t base = (size_t)mt * TILE_HW;
    {   // K fragment
        int m  = mt * 32 + (lane & 31);
        int d0 = f8 * 16 + (lane >> 5) * 8;
        const float* src = mem + (size_t)m * D_DIM + d0;
        #pragma unroll
        for (int e = 0; e < 8; ++e)
            kv[base + f8 * 512 + lane * 8 + e] = f32_to_f16_bits(src[e]);
    }
    {   // V^T fragment
        int dt = fi & 3, ks = (fi >> 2) & 1;
        int d  = dt * 32 + (lane & 31);
        int m0 = mt * 32 + ks * 16 + (lane >> 5) * 8;
        #pragma unroll
        for (int e = 0; e < 8; ++e)
            kv[base + 4096 + f8 * 512 + lane * 8 + e] =
                f32_to_f16_bits(mem[(size_t)(m0 + e) * D_DIM + d]);
    }
}

// ---------------------------------------------------------------------------
// Main kernel: 512 blocks x 256 threads (4 waves). Block bx: q-chunk bx>>1,
// memory half bx&1 (64 tiles). LDS double-buffered 16KB tiles (32 KB).
// ---------------------------------------------------------------------------

#define STAGE(t_, wb_) do {                                                   \
    const char* g_ = (const char*)(kv + (size_t)(tilebase + (t_)) * TILE_HW); \
    char* l_ = (char*)&sbuf[wb_][0];                                          \
    _Pragma("unroll")                                                         \
    for (int j_ = 0; j_ < 4; ++j_) {                                          \
        int ch_ = wave * 4 + j_;                                              \
        __builtin_amdgcn_global_load_lds(                                     \
            (const AS1 char*)(g_ + ch_ * 1024 + lane * 16),                   \
            (AS3 char*)(l_ + ch_ * 1024), 16, 0, 0);                          \
    }                                                                         \
} while (0)

#define MFMA_F16(a_, b_, c_) __builtin_amdgcn_mfma_f32_32x32x16_f16(a_, b_, c_, 0, 0, 0)

#define PSTORE_TILE(Ot_, t_) do {                                             \
    _Pragma("unroll")                                                         \
    for (int g_ = 0; g_ < 4; ++g_) {                                          \
        float4 v_ = { Ot_[4*g_+0], Ot_[4*g_+1], Ot_[4*g_+2], Ot_[4*g_+3] };   \
        int d_ = (t_) * 32 + 8 * g_ + 4 * hi32;                               \
        *(float4*)(prow + d_) = v_;                                           \
    }                                                                         \
} while (0)

__global__ __launch_bounds__(256, 2)
void attn_main(const float* __restrict__ qin,
               const uint16_t* __restrict__ kv,
               float* __restrict__ out0,      // part-0 un-normalized O (= d_out)
               float* __restrict__ pout1,     // [B_ROWS][128] part-1 partial
               float2* __restrict__ pml) {    // [2][B_ROWS] (m, l)
    __shared__ uint16_t sbuf[2][TILE_HW];   // 2 x 16 KB = 32 KB

    const int lane = threadIdx.x & 63;
    const int wave = threadIdx.x >> 6;
    const int half = blockIdx.x & 1;
    const int tilebase = half * HALF_TILES;
    const int q0   = (blockIdx.x >> 1) * 128 + wave * 32;
    const int qrow = q0 + (lane & 31);
    const int hi32 = lane >> 5;

    // Q prep: scale by log2(e), convert to fp16 (B-frag of Sᵀ MFMA).
    f16x8 qh[8];
    {
        const float LOG2E = 1.44269504088896340736f;
        #pragma unroll
        for (int kk = 0; kk < 8; ++kk) {
            const float* src = qin + (size_t)qrow * D_DIM + kk * 16 + hi32 * 8;
            float4 a = *(const float4*)(src);
            float4 b = *(const float4*)(src + 4);
            float xs[8] = {a.x, a.y, a.z, a.w, b.x, b.y, b.z, b.w};
            #pragma unroll
            for (int e = 0; e < 8; ++e)
                qh[kk][e] = (_Float16)(xs[e] * LOG2E);
        }
    }

    f32x16 O0, O1, O2, O3;
    #pragma unroll
    for (int i = 0; i < 16; ++i) { O0[i]=0.f; O1[i]=0.f; O2[i]=0.f; O3[i]=0.f; }
    float m_run = -1e30f, l_run = 0.f;

    STAGE(0, 0);
    __syncthreads();

    #pragma unroll 1
    for (int t = 0; t < HALF_TILES; ++t) {
        const int rb = t & 1;
        if (t + 1 < HALF_TILES) STAGE(t + 1, rb ^ 1);
        const uint16_t* bp = &sbuf[rb][0] + lane * 8;

        // ---- batch the 8 K-fragment reads, then QK^T as two 4-deep chains ----
        f16x8 kh[8];
        #pragma unroll
        for (int kk = 0; kk < 8; ++kk)
            kh[kk] = *(const f16x8*)(bp + kk * 512);

        f32x16 sA, sB;
        #pragma unroll
        for (int i = 0; i < 16; ++i) { sA[i] = 0.f; sB[i] = 0.f; }
        __builtin_amdgcn_s_setprio(1);
        sA = MFMA_F16(kh[0], qh[0], sA);
        sB = MFMA_F16(kh[1], qh[1], sB);
        sA = MFMA_F16(kh[2], qh[2], sA);
        sB = MFMA_F16(kh[3], qh[3], sB);
        sA = MFMA_F16(kh[4], qh[4], sA);
        sB = MFMA_F16(kh[5], qh[5], sB);
        sA = MFMA_F16(kh[6], qh[6], sA);
        sB = MFMA_F16(kh[7], qh[7], sB);
        __builtin_amdgcn_s_setprio(0);
        f32x16 s = sA + sB;   // Sᵀ[m][q], log2-domain logits

        // ---- online softmax (q = lane&31; pair lane lane^32 has other 16 m) ----
        {
            float a0=fmaxf(s[0],s[1]),  a1=fmaxf(s[2],s[3]);
            float a2=fmaxf(s[4],s[5]),  a3=fmaxf(s[6],s[7]);
            float a4=fmaxf(s[8],s[9]),  a5=fmaxf(s[10],s[11]);
            float a6=fmaxf(s[12],s[13]),a7=fmaxf(s[14],s[15]);
            float tmax = fmaxf(fmaxf(fmaxf(a0,a1),fmaxf(a2,a3)),
                               fmaxf(fmaxf(a4,a5),fmaxf(a6,a7)));
            tmax = fmaxf(tmax, __shfl_xor(tmax, 32));
            if (__any(tmax > m_run + 8.0f)) {     // defer-max (T13)
                float mn = fmaxf(m_run, tmax);
                float fr = EXP2F(m_run - mn);
                m_run = mn; l_run *= fr;
                #pragma unroll
                for (int r = 0; r < 16; ++r) {
                    O0[r] *= fr; O1[r] *= fr; O2[r] *= fr; O3[r] *= fr;
                }
            }
        }
        #pragma unroll
        for (int r = 0; r < 16; ++r) s[r] = EXP2F(s[r] - m_run);
        {
            float q0s=s[0]+s[1],  q1s=s[2]+s[3],  q2s=s[4]+s[5],  q3s=s[6]+s[7];
            float q4s=s[8]+s[9],  q5s=s[10]+s[11],q6s=s[12]+s[13],q7s=s[14]+s[15];
            l_run += ((q0s+q1s)+(q2s+q3s)) + ((q4s+q5s)+(q6s+q7s));
        }

        // ---- P(f32) -> fp16 B-frags via v_cvt_pkrtz + permlane32_swap (T12) ----
        u32 c_[8];
        #pragma unroll
        for (int j = 0; j < 8; ++j)
            asm("v_cvt_pkrtz_f16_f32 %0, %1, %2"
                : "=v"(c_[j]) : "v"(s[2*j]), "v"(s[2*j+1]));
        asm("v_permlane32_swap_b32 %0, %1" : "+v"(c_[0]), "+v"(c_[2]));
        asm("v_permlane32_swap_b32 %0, %1" : "+v"(c_[1]), "+v"(c_[3]));
        asm("v_permlane32_swap_b32 %0, %1" : "+v"(c_[4]), "+v"(c_[6]));
        asm("v_permlane32_swap_b32 %0, %1" : "+v"(c_[5]), "+v"(c_[7]));
        f16x8 pf0, pf1;
        { u32 w[4] = {c_[0], c_[1], c_[2], c_[3]}; __builtin_memcpy(&pf0, w, 16); }
        { u32 w[4] = {c_[4], c_[5], c_[6], c_[7]}; __builtin_memcpy(&pf1, w, 16); }

        // ---- PV: batch the 8 V reads, then 8 MFMAs (4 parallel O chains) ----
        f16x8 vf[8];
        #pragma unroll
        for (int f = 0; f < 8; ++f)
            vf[f] = *(const f16x8*)(bp + 4096 + f * 512);
        __builtin_amdgcn_s_setprio(1);
        O0 = MFMA_F16(vf[0], pf0, O0);
        O1 = MFMA_F16(vf[1], pf0, O1);
        O2 = MFMA_F16(vf[2], pf0, O2);
        O3 = MFMA_F16(vf[3], pf0, O3);
        O0 = MFMA_F16(vf[4], pf1, O0);
        O1 = MFMA_F16(vf[5], pf1, O1);
        O2 = MFMA_F16(vf[6], pf1, O2);
        O3 = MFMA_F16(vf[7], pf1, O3);
        __builtin_amdgcn_s_setprio(0);
        __syncthreads();
    }

    // ---- partial store (un-normalized O, plus m,l) ----
    l_run += __shfl_xor(l_run, 32);     // pair-lane partial sums
    float* prow = (half == 0 ? out0 : pout1) + (size_t)qrow * D_DIM;
    PSTORE_TILE(O0, 0); PSTORE_TILE(O1, 1);
    PSTORE_TILE(O2, 2); PSTORE_TILE(O3, 3);
    if (lane < 32) {
        pml[(size_t)half * B_ROWS + qrow] = make_float2(m_run, l_run);
    }
}

// ---------------------------------------------------------------------------
// Merge: out = (P0*w0 + P1*w1) / (l0*w0 + l1*w1), w_i = exp2(m_i - max).
// P0 lives in d_out (in-place read-modify-write per thread's own float4).
// ---------------------------------------------------------------------------
__global__ __launch_bounds__(256)
void merge_halves(const float* __restrict__ pout1,
                  const float2* __restrict__ pml,
                  float* __restrict__ out) {
    int idx  = blockIdx.x * 256 + threadIdx.x;   // 0 .. 2^20-1
    int row  = idx >> 5;
    int c4   = idx & 31;
    float2 a = pml[row];
    float2 b = pml[B_ROWS + row];
    float mn = fmaxf(a.x, b.x);
    float wa = EXP2F(a.x - mn);
    float wb = EXP2F(b.x - mn);
    float rinv = 1.0f / (a.y * wa + b.y * wb);
    float4* O = (float4*)(out + (size_t)row * D_DIM) + c4;
    const float4* P1 = (const float4*)(pout1 + (size_t)row * D_DIM) + c4;
    float4 p0 = *O, p1 = *P1;
    float4 v;
    v.x = (p0.x * wa + p1.x * wb) * rinv;
    v.y = (p0.y * wa + p1.y * wb) * rinv;
    v.z = (p0.z * wa + p1.z * wb) * rinv;
    v.w = (p0.w * wa + p1.w * wb) * rinv;
    *O = v;
}

extern "C" void kernel_launch(void* const* d_in, const int* in_sizes, int n_in,
                              void* d_out, int out_size, void* d_ws, size_t ws_size,
                              hipStream_t stream) {
    const float* local_stats = (const float*)d_in[0];   // [32768,128] f32
    const float* memory      = (const float*)d_in[1];   // [4096,128]  f32
    float* out = (float*)d_out;                         // [32768,128] f32

    // ws layout: kv frags 2MB | part-1 partial O 16MB | pml 0.5MB
    uint16_t* kv   = (uint16_t*)d_ws;
    float*   pout1 = (float*)((char*)d_ws + 2 * 1024 * 1024);
    float2*  pml   = (float2*)((char*)pout1 + (size_t)B_ROWS * D_DIM * 4);

    prep_frags<<<256, 256, 0, stream>>>(memory, kv);
    attn_main<<<512, 256, 0, stream>>>(local_stats, kv, out, pout1, pml);
    merge_halves<<<4096, 256, 0, stream>>>(pout1, pml, out);
}

// Round 14
// 101.394 us; speedup vs baseline: 1.7307x; 1.0267x over previous
//
#include <hip/hip_runtime.h>
#include <hip/hip_bf16.h>
#include <stdint.h>

// B=32768 queries, M=4096 memory rows, D=128.
//   logits = Q @ M^T ; attn = softmax(logits) ; out = attn @ M
// v13: fp16 flash kernel + 2-tiles-per-barrier phase overlap.
// v12b's counters (Mfma 29 + VALU 32 + LDS ~40 ~= 100%, nothing saturated)
// show serialized phases under per-tile barrier quantization. Now one
// barrier interval covers TWO tiles: QK(t) -> QK(t+1) -> softmax(t)+PV(t)
// -> softmax(t+1)+PV(t+1). QK(t+1) MFMAs overlap softmax(t) VALU; PV(t)
// overlaps softmax(t+1). 4 LDS buffers (64KB; 2 blocks/CU = 128KB).
// Nothing crosses a barrier in registers -> peak ~246 unified, no spill
// (v10's failure mode). Same skeleton: 512 blocks, 2-way M-split, merge.

typedef float    f32x16 __attribute__((ext_vector_type(16)));
typedef _Float16 f16x8  __attribute__((ext_vector_type(8)));
typedef uint32_t u32;

#define AS1 __attribute__((address_space(1)))
#define AS3 __attribute__((address_space(3)))

#define D_DIM 128
#define B_ROWS 32768
#define TILE_HW 8192      // halfwords per 32-row tile: [K 4096 | V 4096]
#define HALF_TILES 64     // tiles per block

#if __has_builtin(__builtin_amdgcn_exp2f)
#define EXP2F(x) __builtin_amdgcn_exp2f(x)
#else
#define EXP2F(x) exp2f(x)
#endif

__device__ __forceinline__ uint16_t f32_to_f16_bits(float x) {
    _Float16 h = (_Float16)x;
    uint16_t r; __builtin_memcpy(&r, &h, 2);
    return r;
}

// ---------------------------------------------------------------------------
// Prep: memory -> fragment-linear fp16 tiles in d_ws.
// Per tile mt (16384 B): [0,8K) K frags, [8K,16K) V^T frags.
// ---------------------------------------------------------------------------
__global__ void prep_frags(const float* __restrict__ mem,
                           uint16_t* __restrict__ kv) {
    int t = blockIdx.x * blockDim.x + threadIdx.x;  // 0..65535
    int lane = t & 63;
    int fi = t >> 6;                                // 0..1023
    int f8 = fi & 7, mt = fi >> 3;
    size_t base = (size_t)mt * TILE_HW;
    {   // K fragment
        int m  = mt * 32 + (lane & 31);
        int d0 = f8 * 16 + (lane >> 5) * 8;
        const float* src = mem + (size_t)m * D_DIM + d0;
        #pragma unroll
        for (int e = 0; e < 8; ++e)
            kv[base + f8 * 512 + lane * 8 + e] = f32_to_f16_bits(src[e]);
    }
    {   // V^T fragment
        int dt = fi & 3, ks = (fi >> 2) & 1;
        int d  = dt * 32 + (lane & 31);
        int m0 = mt * 32 + ks * 16 + (lane >> 5) * 8;
        #pragma unroll
        for (int e = 0; e < 8; ++e)
            kv[base + 4096 + f8 * 512 + lane * 8 + e] =
                f32_to_f16_bits(mem[(size_t)(m0 + e) * D_DIM + d]);
    }
}

// ---------------------------------------------------------------------------
// Main kernel: 512 blocks x 256 threads (4 waves). Block bx: q-chunk bx>>1,
// memory half bx&1 (64 tiles). LDS 4 x 16KB buffers, 2 tiles per barrier.
// ---------------------------------------------------------------------------

#define STAGE(t_, wb_) do {                                                   \
    const char* g_ = (const char*)(kv + (size_t)(tilebase + (t_)) * TILE_HW); \
    char* l_ = (char*)&sbuf[wb_][0];                                          \
    _Pragma("unroll")                                                         \
    for (int j_ = 0; j_ < 4; ++j_) {                                          \
        int ch_ = wave * 4 + j_;                                              \
        __builtin_amdgcn_global_load_lds(                                     \
            (const AS1 char*)(g_ + ch_ * 1024 + lane * 16),                   \
            (AS3 char*)(l_ + ch_ * 1024), 16, 0, 0);                          \
    }                                                                         \
} while (0)

#define MFMA_F16(a_, b_, c_) __builtin_amdgcn_mfma_f32_32x32x16_f16(a_, b_, c_, 0, 0, 0)

// QK^T for one tile: batch 8 K reads, two 4-deep chains -> s_.
#define QK(bp_, s_) do {                                                      \
    f16x8 kh_[8];                                                             \
    _Pragma("unroll")                                                         \
    for (int kk_ = 0; kk_ < 8; ++kk_)                                         \
        kh_[kk_] = *(const f16x8*)((bp_) + kk_ * 512);                        \
    f32x16 sA_, sB_;                                                          \
    _Pragma("unroll")                                                         \
    for (int i_ = 0; i_ < 16; ++i_) { sA_[i_] = 0.f; sB_[i_] = 0.f; }         \
    sA_ = MFMA_F16(kh_[0], qh[0], sA_);                                       \
    sB_ = MFMA_F16(kh_[1], qh[1], sB_);                                       \
    sA_ = MFMA_F16(kh_[2], qh[2], sA_);                                       \
    sB_ = MFMA_F16(kh_[3], qh[3], sB_);                                       \
    sA_ = MFMA_F16(kh_[4], qh[4], sA_);                                       \
    sB_ = MFMA_F16(kh_[5], qh[5], sB_);                                       \
    sA_ = MFMA_F16(kh_[6], qh[6], sA_);                                       \
    sB_ = MFMA_F16(kh_[7], qh[7], sB_);                                       \
    s_ = sA_ + sB_;                                                           \
} while (0)

// Online softmax on s_ (Sᵀ layout) then PV of the same tile.
#define SMX_PV(s_, bp_) do {                                                  \
    float a0=fmaxf(s_[0],s_[1]),  a1=fmaxf(s_[2],s_[3]);                      \
    float a2=fmaxf(s_[4],s_[5]),  a3=fmaxf(s_[6],s_[7]);                      \
    float a4=fmaxf(s_[8],s_[9]),  a5=fmaxf(s_[10],s_[11]);                    \
    float a6=fmaxf(s_[12],s_[13]),a7=fmaxf(s_[14],s_[15]);                    \
    float tmax = fmaxf(fmaxf(fmaxf(a0,a1),fmaxf(a2,a3)),                      \
                       fmaxf(fmaxf(a4,a5),fmaxf(a6,a7)));                     \
    tmax = fmaxf(tmax, __shfl_xor(tmax, 32));                                 \
    if (__any(tmax > m_run + 8.0f)) {     /* defer-max (T13) */               \
        float mn = fmaxf(m_run, tmax);                                        \
        float fr = EXP2F(m_run - mn);                                         \
        m_run = mn; l_run *= fr;                                              \
        _Pragma("unroll")                                                     \
        for (int r_ = 0; r_ < 16; ++r_) {                                     \
            O0[r_] *= fr; O1[r_] *= fr; O2[r_] *= fr; O3[r_] *= fr;           \
        }                                                                     \
    }                                                                         \
    _Pragma("unroll")                                                         \
    for (int r_ = 0; r_ < 16; ++r_) s_[r_] = EXP2F(s_[r_] - m_run);           \
    { float q0s=s_[0]+s_[1],  q1s=s_[2]+s_[3],  q2s=s_[4]+s_[5],  q3s=s_[6]+s_[7];   \
      float q4s=s_[8]+s_[9],  q5s=s_[10]+s_[11],q6s=s_[12]+s_[13],q7s=s_[14]+s_[15]; \
      l_run += ((q0s+q1s)+(q2s+q3s)) + ((q4s+q5s)+(q6s+q7s)); }               \
    u32 c_[8];                                                                \
    _Pragma("unroll")                                                         \
    for (int j_ = 0; j_ < 8; ++j_)                                            \
        asm("v_cvt_pkrtz_f16_f32 %0, %1, %2"                                  \
            : "=v"(c_[j_]) : "v"(s_[2*j_]), "v"(s_[2*j_+1]));                 \
    asm("v_permlane32_swap_b32 %0, %1" : "+v"(c_[0]), "+v"(c_[2]));           \
    asm("v_permlane32_swap_b32 %0, %1" : "+v"(c_[1]), "+v"(c_[3]));           \
    asm("v_permlane32_swap_b32 %0, %1" : "+v"(c_[4]), "+v"(c_[6]));           \
    asm("v_permlane32_swap_b32 %0, %1" : "+v"(c_[5]), "+v"(c_[7]));           \
    f16x8 pf0_, pf1_;                                                         \
    { u32 w_[4] = {c_[0], c_[1], c_[2], c_[3]}; __builtin_memcpy(&pf0_, w_, 16); } \
    { u32 w_[4] = {c_[4], c_[5], c_[6], c_[7]}; __builtin_memcpy(&pf1_, w_, 16); } \
    f16x8 vf_[8];                                                             \
    _Pragma("unroll")                                                         \
    for (int f_ = 0; f_ < 8; ++f_)                                            \
        vf_[f_] = *(const f16x8*)((bp_) + 4096 + f_ * 512);                   \
    O0 = MFMA_F16(vf_[0], pf0_, O0);                                          \
    O1 = MFMA_F16(vf_[1], pf0_, O1);                                          \
    O2 = MFMA_F16(vf_[2], pf0_, O2);                                          \
    O3 = MFMA_F16(vf_[3], pf0_, O3);                                          \
    O0 = MFMA_F16(vf_[4], pf1_, O0);                                          \
    O1 = MFMA_F16(vf_[5], pf1_, O1);                                          \
    O2 = MFMA_F16(vf_[6], pf1_, O2);                                          \
    O3 = MFMA_F16(vf_[7], pf1_, O3);                                          \
} while (0)

#define PSTORE_TILE(Ot_, t_) do {                                             \
    _Pragma("unroll")                                                         \
    for (int g_ = 0; g_ < 4; ++g_) {                                          \
        float4 v_ = { Ot_[4*g_+0], Ot_[4*g_+1], Ot_[4*g_+2], Ot_[4*g_+3] };   \
        int d_ = (t_) * 32 + 8 * g_ + 4 * hi32;                               \
        *(float4*)(prow + d_) = v_;                                           \
    }                                                                         \
} while (0)

__global__ __launch_bounds__(256, 2)
void attn_main(const float* __restrict__ qin,
               const uint16_t* __restrict__ kv,
               float* __restrict__ out0,      // part-0 un-normalized O (= d_out)
               float* __restrict__ pout1,     // [B_ROWS][128] part-1 partial
               float2* __restrict__ pml) {    // [2][B_ROWS] (m, l)
    __shared__ uint16_t sbuf[4][TILE_HW];   // 4 x 16 KB = 64 KB

    const int lane = threadIdx.x & 63;
    const int wave = threadIdx.x >> 6;
    const int half = blockIdx.x & 1;
    const int tilebase = half * HALF_TILES;
    const int q0   = (blockIdx.x >> 1) * 128 + wave * 32;
    const int qrow = q0 + (lane & 31);
    const int hi32 = lane >> 5;

    // Q prep: scale by log2(e), convert to fp16 (B-frag of Sᵀ MFMA).
    f16x8 qh[8];
    {
        const float LOG2E = 1.44269504088896340736f;
        #pragma unroll
        for (int kk = 0; kk < 8; ++kk) {
            const float* src = qin + (size_t)qrow * D_DIM + kk * 16 + hi32 * 8;
            float4 a = *(const float4*)(src);
            float4 b = *(const float4*)(src + 4);
            float xs[8] = {a.x, a.y, a.z, a.w, b.x, b.y, b.z, b.w};
            #pragma unroll
            for (int e = 0; e < 8; ++e)
                qh[kk][e] = (_Float16)(xs[e] * LOG2E);
        }
    }

    f32x16 O0, O1, O2, O3;
    #pragma unroll
    for (int i = 0; i < 16; ++i) { O0[i]=0.f; O1[i]=0.f; O2[i]=0.f; O3[i]=0.f; }
    float m_run = -1e30f, l_run = 0.f;

    STAGE(0, 0);
    STAGE(1, 1);
    __syncthreads();

    // 2 tiles per barrier interval. Buffers (t+2)&3,(t+3)&3 were consumed
    // in the PREVIOUS interval (barrier protects WAR); they are restaged
    // here and consumed next interval (barrier's vmcnt-drain protects RAW).
    #pragma unroll 1
    for (int t = 0; t < HALF_TILES; t += 2) {
        if (t + 2 < HALF_TILES) STAGE(t + 2, (t + 2) & 3);
        if (t + 3 < HALF_TILES) STAGE(t + 3, (t + 3) & 3);
        const uint16_t* bp0 = &sbuf[t & 3][0] + lane * 8;
        const uint16_t* bp1 = &sbuf[(t + 1) & 3][0] + lane * 8;

        f32x16 s0, s1;
        QK(bp0, s0);          // tile t
        QK(bp1, s1);          // tile t+1 — MFMAs overlap softmax(t) below
        SMX_PV(s0, bp0);      // softmax(t) + PV(t); overlaps QK/softmax(t+1)
        SMX_PV(s1, bp1);      // softmax(t+1) + PV(t+1)
        __syncthreads();
    }

    // ---- partial store (un-normalized O, plus m,l) ----
    l_run += __shfl_xor(l_run, 32);     // pair-lane partial sums
    float* prow = (half == 0 ? out0 : pout1) + (size_t)qrow * D_DIM;
    PSTORE_TILE(O0, 0); PSTORE_TILE(O1, 1);
    PSTORE_TILE(O2, 2); PSTORE_TILE(O3, 3);
    if (lane < 32) {
        pml[(size_t)half * B_ROWS + qrow] = make_float2(m_run, l_run);
    }
}

// ---------------------------------------------------------------------------
// Merge: out = (P0*w0 + P1*w1) / (l0*w0 + l1*w1), w_i = exp2(m_i - max).
// P0 lives in d_out (in-place read-modify-write per thread's own float4).
// ---------------------------------------------------------------------------
__global__ __launch_bounds__(256)
void merge_halves(const float* __restrict__ pout1,
                  const float2* __restrict__ pml,
                  float* __restrict__ out) {
    int idx  = blockIdx.x * 256 + threadIdx.x;   // 0 .. 2^20-1
    int row  = idx >> 5;
    int c4   = idx & 31;
    float2 a = pml[row];
    float2 b = pml[B_ROWS + row];
    float mn = fmaxf(a.x, b.x);
    float wa = EXP2F(a.x - mn);
    float wb = EXP2F(b.x - mn);
    float rinv = 1.0f / (a.y * wa + b.y * wb);
    float4* O = (float4*)(out + (size_t)row * D_DIM) + c4;
    const float4* P1 = (const float4*)(pout1 + (size_t)row * D_DIM) + c4;
    float4 p0 = *O, p1 = *P1;
    float4 v;
    v.x = (p0.x * wa + p1.x * wb) * rinv;
    v.y = (p0.y * wa + p1.y * wb) * rinv;
    v.z = (p0.z * wa + p1.z * wb) * rinv;
    v.w = (p0.w * wa + p1.w * wb) * rinv;
    *O = v;
}

extern "C" void kernel_launch(void* const* d_in, const int* in_sizes, int n_in,
                              void* d_out, int out_size, void* d_ws, size_t ws_size,
                              hipStream_t stream) {
    const float* local_stats = (const float*)d_in[0];   // [32768,128] f32
    const float* memory      = (const float*)d_in[1];   // [4096,128]  f32
    float* out = (float*)d_out;                         // [32768,128] f32

    // ws layout: kv frags 2MB | part-1 partial O 16MB | pml 0.5MB
    uint16_t* kv   = (uint16_t*)d_ws;
    float*   pout1 = (float*)((char*)d_ws + 2 * 1024 * 1024);
    float2*  pml   = (float2*)((char*)pout1 + (size_t)B_ROWS * D_DIM * 4);

    prep_frags<<<256, 256, 0, stream>>>(memory, kv);
    attn_main<<<512, 256, 0, stream>>>(local_stats, kv, out, pout1, pml);
    merge_halves<<<4096, 256, 0, stream>>>(pout1, pml, out);
}